// Round 7
// baseline (181.281 us; speedup 1.0000x reference)
//
#include <hip/hip_runtime.h>
#include <hip/hip_bf16.h>

// MultiLatentAttention on MI355X.
// causal mask t<=l with L=64 => attention only over first 64 tokens.
// out[b] = softmax_groups(x@Wg) @ M[b],  M built from attn_out and Wp.

typedef __attribute__((ext_vector_type(8))) short bf16x8;
typedef __attribute__((ext_vector_type(4))) float f32x4;
typedef __attribute__((ext_vector_type(4))) unsigned short us4;

__device__ __forceinline__ void gll16(const void* g, void* l) {
  __builtin_amdgcn_global_load_lds((const __attribute__((address_space(1))) void*)g,
                                   (__attribute__((address_space(3))) void*)l, 16, 0, 0);
}

// ---------------- prep: x->bf16 (blocks 0..2047) + 3 weight transposes (blocks 2048..5119) ----
__global__ __launch_bounds__(256)
void prep_kernel(const float* __restrict__ x, __hip_bfloat16* __restrict__ xb,
                 const float* __restrict__ Wg, const float* __restrict__ Wk,
                 const float* __restrict__ Wv,
                 __hip_bfloat16* __restrict__ WgT, __hip_bfloat16* __restrict__ WkT,
                 __hip_bfloat16* __restrict__ WvT) {
  const int bid = blockIdx.x, tid = threadIdx.x;
  if (bid < 2048) {
    const int stride = 2048 * 256;
    for (int i = bid * 256 + tid; i < 4194304; i += stride) {
      float4 f = reinterpret_cast<const float4*>(x)[i];
      union { __hip_bfloat16 h[4]; us4 v; } u;
      u.h[0] = __float2bfloat16(f.x);
      u.h[1] = __float2bfloat16(f.y);
      u.h[2] = __float2bfloat16(f.z);
      u.h[3] = __float2bfloat16(f.w);
      reinterpret_cast<us4*>(xb)[i] = u.v;
    }
  } else {
    const int t = bid - 2048;
    const int z = t >> 10, rem = t & 1023;
    const float* W = (z == 0) ? Wg : ((z == 1) ? Wk : Wv);
    __hip_bfloat16* Wt = (z == 0) ? WgT : ((z == 1) ? WkT : WvT);
    __shared__ float tile[32][33];
    const int bx = (rem & 31) * 32, by = (rem >> 5) * 32;
    const int tx = tid & 31, ty = tid >> 5;  // 32x8
    #pragma unroll
    for (int j = 0; j < 32; j += 8)
      tile[ty + j][tx] = W[(size_t)(by + ty + j) * 1024 + bx + tx];
    __syncthreads();
    #pragma unroll
    for (int j = 0; j < 32; j += 8)
      Wt[(size_t)(bx + ty + j) * 1024 + by + tx] = __float2bfloat16(tile[tx][ty + j]);
  }
}

// ---------------- 256x256 depth-3 counted-vmcnt pipeline (BK=32, 4 LDS bufs) ----------------
// 8 waves (2Mx4N). Per K-step: vmcnt(8) [2 tiles in flight, never 0] -> s_barrier ->
// {issue STAGE(t+3) || 12 ds_read || 32 MFMA} compiler-scheduled. One barrier/iter.
// Buffer rotation depth 4: stage(t+3) writes buf[(t+3)&3], last read at iter t-1,
// separated by this iter's barrier (per-wave lgkm drained by MFMA deps). Tail stages
// wrap (garbage, never read, keep vmcnt math uniform).
// Row = 64B = 4 chunks; swizzle slot ^= (row&3)^((row>>2)&3): 16 frag-lanes spread
// over each bank-quad exactly 2x (2-way = free). Applied pre-swizzled on the GLOBAL
// source (gll16 dest linear) and on fragment reads.
// EPI=0: fp32 store. EPI=1: per-64-column-group softmax, bf16 store (gates).
template <int EPI>
__global__ __launch_bounds__(512)
void pipe256(const __hip_bfloat16* __restrict__ A, const __hip_bfloat16* __restrict__ Bt,
             void* __restrict__ Cv, int K, int ldc,
             long long astride, long long bstride, long long cstride) {
  __shared__ __align__(16) unsigned short SA[4][256 * 32];
  __shared__ __align__(16) unsigned short SB[4][256 * 32];
  const int tid = threadIdx.x;
  const int lane = tid & 63;
  const int w = tid >> 6;            // wave 0..7
  const int wm = w >> 2, wn = w & 3; // 2x4 wave grid; per-wave out = 128x64
  const int lr = lane & 15, lk = lane >> 4;
  const int m0 = blockIdx.x * 256, n0 = blockIdx.y * 256;
  const long long b = blockIdx.z;
  const __hip_bfloat16* Ab = A + b * astride;
  const __hip_bfloat16* Bb = Bt + b * bstride;

  f32x4 acc[8][4] = {};

  // stage one K-tile (256 rows x 32 k) of A and B: 2 chunks each per thread
  auto STAGE = [&](int bsel, int kt) {
    #pragma unroll
    for (int r = 0; r < 2; ++r) {
      int c = r * 512 + tid;          // chunk 0..1023: row=c>>2, slot=c&3
      int row = c >> 2, slot = c & 3;
      int gs = slot ^ (row & 3) ^ ((row >> 2) & 3);  // pre-swizzled global slot
      gll16(Ab + (size_t)(m0 + row) * K + kt + gs * 8, (char*)&SA[bsel][0] + c * 16);
      gll16(Bb + (size_t)(n0 + row) * K + kt + gs * 8, (char*)&SB[bsel][0] + c * 16);
    }
  };

  const int NT = K >> 5;  // 32 K-steps

  // prologue: prefetch tiles 0,1,2 (12 loads/thread outstanding)
  STAGE(0, 0);
  STAGE(1, 32);
  STAGE(2, 64);

  for (int t = 0; t < NT; ++t) {
    asm volatile("s_waitcnt vmcnt(8)" ::: "memory");  // tile t landed; t+1,t+2 in flight
    __builtin_amdgcn_s_barrier();
    __builtin_amdgcn_sched_barrier(0);

    int kt = (t + 3) << 5; if (kt >= K) kt -= K;      // tail: garbage re-stage (never read)
    STAGE((t + 3) & 3, kt);

    const int buf = t & 3;
    bf16x8 bfr[4];
    #pragma unroll
    for (int ni = 0; ni < 4; ++ni) {
      int row = wn * 64 + ni * 16 + lr;
      int s = lk ^ (row & 3) ^ ((row >> 2) & 3);
      bfr[ni] = *(const bf16x8*)&SB[buf][row * 32 + s * 8];
    }
    #pragma unroll
    for (int mi = 0; mi < 8; ++mi) {
      int row = wm * 128 + mi * 16 + lr;
      int s = lk ^ (row & 3) ^ ((row >> 2) & 3);
      bf16x8 a = *(const bf16x8*)&SA[buf][row * 32 + s * 8];
      #pragma unroll
      for (int ni = 0; ni < 4; ++ni)
        acc[mi][ni] = __builtin_amdgcn_mfma_f32_16x16x32_bf16(a, bfr[ni], acc[mi][ni], 0, 0, 0);
    }
  }
  asm volatile("s_waitcnt vmcnt(0)" ::: "memory");  // drain tail garbage stages

  if (EPI == 0) {
    float* C = (float*)Cv + b * cstride;
    #pragma unroll
    for (int mi = 0; mi < 8; ++mi) {
      int r = m0 + wm * 128 + mi * 16 + lk * 4;
      #pragma unroll
      for (int ni = 0; ni < 4; ++ni) {
        int c = n0 + wn * 64 + ni * 16 + lr;
        #pragma unroll
        for (int jj = 0; jj < 4; ++jj)
          C[(size_t)(r + jj) * ldc + c] = acc[mi][ni][jj];
      }
    }
  } else {
    // Each wave's 64 columns = one softmax group (head h, l=0..63).
    __hip_bfloat16* C = (__hip_bfloat16*)Cv + b * cstride;
    #pragma unroll
    for (int mi = 0; mi < 8; ++mi) {
      #pragma unroll
      for (int jj = 0; jj < 4; ++jj) {
        float mx = -3.0e38f;
        #pragma unroll
        for (int ni = 0; ni < 4; ++ni) mx = fmaxf(mx, acc[mi][ni][jj]);
        mx = fmaxf(mx, __shfl_xor(mx, 1));
        mx = fmaxf(mx, __shfl_xor(mx, 2));
        mx = fmaxf(mx, __shfl_xor(mx, 4));
        mx = fmaxf(mx, __shfl_xor(mx, 8));
        float e[4];
        float s = 0.f;
        #pragma unroll
        for (int ni = 0; ni < 4; ++ni) { e[ni] = __expf(acc[mi][ni][jj] - mx); s += e[ni]; }
        s += __shfl_xor(s, 1);
        s += __shfl_xor(s, 2);
        s += __shfl_xor(s, 4);
        s += __shfl_xor(s, 8);
        float inv = 1.0f / s;
        int r = m0 + wm * 128 + mi * 16 + lk * 4 + jj;
        #pragma unroll
        for (int ni = 0; ni < 4; ++ni)
          C[(size_t)r * ldc + n0 + wn * 64 + ni * 16 + lr] = __float2bfloat16(e[ni] * inv);
      }
    }
  }
}

// ---------------- 256x256 2-phase pipelined bf16 GEMM (proven ~49us) — control arm -----------
template <int EPI>
__global__ __launch_bounds__(512, 2)
void gemm256(const __hip_bfloat16* __restrict__ A, const __hip_bfloat16* __restrict__ Bt,
             void* __restrict__ Cv, int K, int ldc,
             long long astride, long long bstride, long long cstride) {
  __shared__ __align__(16) unsigned short SA[2][256 * 64];
  __shared__ __align__(16) unsigned short SB[2][256 * 64];
  const int tid = threadIdx.x;
  const int lane = tid & 63;
  const int w = tid >> 6;            // wave 0..7
  const int wm = w >> 2, wn = w & 3; // 2x4 wave grid; per-wave out = 128x64
  const int lr = lane & 15, lk = lane >> 4;
  const int m0 = blockIdx.x * 256, n0 = blockIdx.y * 256;
  const long long b = blockIdx.z;
  const __hip_bfloat16* Ab = A + b * astride;
  const __hip_bfloat16* Bb = Bt + b * bstride;

  f32x4 acc[8][4] = {};

  const int NT = K >> 6;
  int buf = 0;

  auto STAGE = [&](int bsel, int kt) {
    #pragma unroll
    for (int r = 0; r < 4; ++r) {
      int c = r * 512 + tid;          // chunk 0..2047: row=c>>3, slot=c&7
      int row = c >> 3, slot = c & 7;
      int gch = slot ^ (row & 7);     // pre-swizzled global chunk
      gll16(Ab + (size_t)(m0 + row) * K + kt + gch * 8, (char*)&SA[bsel][0] + c * 16);
      gll16(Bb + (size_t)(n0 + row) * K + kt + gch * 8, (char*)&SB[bsel][0] + c * 16);
    }
  };

  STAGE(0, 0);
  __syncthreads();

  for (int t = 0; t < NT; ++t) {
    if (t + 1 < NT) STAGE(buf ^ 1, (t + 1) << 6);

    bf16x8 bfr[2][4];
    #pragma unroll
    for (int kk = 0; kk < 2; ++kk)
      #pragma unroll
      for (int ni = 0; ni < 4; ++ni) {
        int row = wn * 64 + ni * 16 + lr;
        int ch = (kk * 4 + lk) ^ (row & 7);
        bfr[kk][ni] = *(const bf16x8*)&SB[buf][row * 64 + ch * 8];
      }
    #pragma unroll
    for (int mi = 0; mi < 8; ++mi) {
      int row = wm * 128 + mi * 16 + lr;
      int ch0 = lk ^ (row & 7);
      int ch1 = (4 + lk) ^ (row & 7);
      bf16x8 a0 = *(const bf16x8*)&SA[buf][row * 64 + ch0 * 8];
      bf16x8 a1 = *(const bf16x8*)&SA[buf][row * 64 + ch1 * 8];
      #pragma unroll
      for (int ni = 0; ni < 4; ++ni)
        acc[mi][ni] = __builtin_amdgcn_mfma_f32_16x16x32_bf16(a0, bfr[0][ni], acc[mi][ni], 0, 0, 0);
      #pragma unroll
      for (int ni = 0; ni < 4; ++ni)
        acc[mi][ni] = __builtin_amdgcn_mfma_f32_16x16x32_bf16(a1, bfr[1][ni], acc[mi][ni], 0, 0, 0);
    }
    __syncthreads();
    buf ^= 1;
  }

  if (EPI == 0) {
    float* C = (float*)Cv + b * cstride;
    #pragma unroll
    for (int mi = 0; mi < 8; ++mi) {
      int r = m0 + wm * 128 + mi * 16 + lk * 4;
      #pragma unroll
      for (int ni = 0; ni < 4; ++ni) {
        int c = n0 + wn * 64 + ni * 16 + lr;
        #pragma unroll
        for (int jj = 0; jj < 4; ++jj)
          C[(size_t)(r + jj) * ldc + c] = acc[mi][ni][jj];
      }
    }
  } else {
    __hip_bfloat16* C = (__hip_bfloat16*)Cv + b * cstride;
    #pragma unroll
    for (int mi = 0; mi < 8; ++mi) {
      #pragma unroll
      for (int jj = 0; jj < 4; ++jj) {
        float mx = -3.0e38f;
        #pragma unroll
        for (int ni = 0; ni < 4; ++ni) mx = fmaxf(mx, acc[mi][ni][jj]);
        mx = fmaxf(mx, __shfl_xor(mx, 1));
        mx = fmaxf(mx, __shfl_xor(mx, 2));
        mx = fmaxf(mx, __shfl_xor(mx, 4));
        mx = fmaxf(mx, __shfl_xor(mx, 8));
        float e[4];
        float s = 0.f;
        #pragma unroll
        for (int ni = 0; ni < 4; ++ni) { e[ni] = __expf(acc[mi][ni][jj] - mx); s += e[ni]; }
        s += __shfl_xor(s, 1);
        s += __shfl_xor(s, 2);
        s += __shfl_xor(s, 4);
        s += __shfl_xor(s, 8);
        float inv = 1.0f / s;
        int r = m0 + wm * 128 + mi * 16 + lk * 4 + jj;
        #pragma unroll
        for (int ni = 0; ni < 4; ++ni)
          C[(size_t)r * ldc + n0 + wn * 64 + ni * 16 + lr] = __float2bfloat16(e[ni] * inv);
      }
    }
  }
}

// ---------------- 128x128 GEMM (small kv projection) ----------------
__global__ __launch_bounds__(256)
void gemm_bt(const __hip_bfloat16* __restrict__ A, const __hip_bfloat16* __restrict__ Bt,
             void* __restrict__ Cv, int K, int ldc,
             long long astride, long long bstride, long long cstride) {
  __shared__ __align__(16) unsigned short As[128 * 32];
  __shared__ __align__(16) unsigned short Bs[128 * 32];
  const int tid = threadIdx.x;
  const int lane = tid & 63;
  const int w = tid >> 6;
  const int wm = w >> 1, wn = w & 1;
  const int lr = lane & 15, lk = lane >> 4;
  const int m0 = blockIdx.x * 128, n0 = blockIdx.y * 128;
  const long long b = blockIdx.z;
  const __hip_bfloat16* Ab = A + b * astride;
  const __hip_bfloat16* Bb = Bt + b * bstride;

  f32x4 acc[4][4] = {};
  const int r0 = tid >> 2;
  const int c8 = (tid & 3) * 8;

  for (int kt = 0; kt < K; kt += 32) {
    __syncthreads();
    gll16(Ab + (size_t)(m0 + r0) * K + kt + c8,       (char*)As + (w * 64) * 16);
    gll16(Bb + (size_t)(n0 + r0) * K + kt + c8,       (char*)Bs + (w * 64) * 16);
    gll16(Ab + (size_t)(m0 + 64 + r0) * K + kt + c8,  (char*)As + (256 + w * 64) * 16);
    gll16(Bb + (size_t)(n0 + 64 + r0) * K + kt + c8,  (char*)Bs + (256 + w * 64) * 16);
    __syncthreads();

    bf16x8 af[4], bf[4];
    #pragma unroll
    for (int mi = 0; mi < 4; ++mi)
      af[mi] = *(const bf16x8*)&As[(wm * 64 + mi * 16 + lr) * 32 + lk * 8];
    #pragma unroll
    for (int ni = 0; ni < 4; ++ni)
      bf[ni] = *(const bf16x8*)&Bs[(wn * 64 + ni * 16 + lr) * 32 + lk * 8];
    #pragma unroll
    for (int mi = 0; mi < 4; ++mi)
      #pragma unroll
      for (int ni = 0; ni < 4; ++ni)
        acc[mi][ni] = __builtin_amdgcn_mfma_f32_16x16x32_bf16(af[mi], bf[ni], acc[mi][ni], 0, 0, 0);
  }

  float* C = (float*)Cv + b * cstride;
  #pragma unroll
  for (int mi = 0; mi < 4; ++mi) {
    int r = m0 + wm * 64 + mi * 16 + lk * 4;
    #pragma unroll
    for (int ni = 0; ni < 4; ++ni) {
      int c = n0 + wn * 64 + ni * 16 + lr;
      #pragma unroll
      for (int jj = 0; jj < 4; ++jj)
        C[(size_t)(r + jj) * ldc + c] = acc[mi][ni][jj];
    }
  }
}

// ---------------- attention (RoPE fused into K staging): per (b,h), 64x64 ----------------
__global__ __launch_bounds__(256)
void attn_kernel(const float* __restrict__ kv, const float* __restrict__ lq,
                 float* __restrict__ ao) {
  int h = blockIdx.x, b = blockIdx.y;
  __shared__ float Ks[64][64];
  __shared__ float Vs[64][64];
  __shared__ float S[64][65];   // S[l][t]
  __shared__ float Pt[64][65];  // Pt[t][l]
  const int tid = threadIdx.x;
  const float* kb = kv + (size_t)b * 128 * 2048 + h * 64;
  const float* vb = kb + 1024;

  {
    int r = tid >> 4;            // 0..15
    int c4 = (tid & 15) * 4;     // head-dim col (pairs i0=c4/2, i0+1)
    int i0 = c4 >> 1;
    float inv0 = exp2f(-13.287712379549449f * ((float)i0 * (1.0f / 32.0f)));
    float inv1 = exp2f(-13.287712379549449f * ((float)(i0 + 1) * (1.0f / 32.0f)));
    #pragma unroll
    for (int j = 0; j < 4; ++j) {
      int row = j * 16 + r;      // t
      float4 kf = *(const float4*)&kb[(size_t)row * 2048 + c4];
      float a0 = (float)row * inv0, a1 = (float)row * inv1;
      float s0 = sinf(a0), c0 = cosf(a0), s1 = sinf(a1), c1 = cosf(a1);
      *(float4*)&Ks[row][c4] = make_float4(kf.x * c0 - kf.y * s0, kf.x * s0 + kf.y * c0,
                                           kf.z * c1 - kf.w * s1, kf.z * s1 + kf.w * c1);
      *(float4*)&Vs[row][c4] = *(const float4*)&vb[(size_t)row * 2048 + c4];
    }
  }
  __syncthreads();

  {
    const int w = tid >> 6, l = tid & 63;
    float q[64];
    const float4* lq4 = (const float4*)(lq + ((size_t)l * 16 + h) * 64);
    #pragma unroll
    for (int i = 0; i < 16; ++i) {
      float4 f = lq4[i];
      q[4 * i] = f.x; q[4 * i + 1] = f.y; q[4 * i + 2] = f.z; q[4 * i + 3] = f.w;
    }
    #pragma unroll
    for (int tl = 0; tl < 16; ++tl) {
      int t = w * 16 + tl;
      float acc = 0.f;
      #pragma unroll
      for (int d4 = 0; d4 < 16; ++d4) {
        float4 kf = *(const float4*)&Ks[t][d4 * 4];
        acc += q[4 * d4] * kf.x + q[4 * d4 + 1] * kf.y + q[4 * d4 + 2] * kf.z + q[4 * d4 + 3] * kf.w;
      }
      S[l][t] = acc * 0.125f;
    }
  }
  __syncthreads();

  {
    const int l = tid >> 2, c = tid & 3;
    float sv[16];
    float mx = -3.0e38f;
    #pragma unroll
    for (int i = 0; i < 16; ++i) {
      int t = c * 16 + i;
      sv[i] = S[l][t];
      if (t <= l) mx = fmaxf(mx, sv[i]);
    }
    mx = fmaxf(mx, __shfl_xor(mx, 1));
    mx = fmaxf(mx, __shfl_xor(mx, 2));
    float sum = 0.f;
    float e[16];
    #pragma unroll
    for (int i = 0; i < 16; ++i) {
      int t = c * 16 + i;
      e[i] = (t <= l) ? __expf(sv[i] - mx) : 0.f;
      sum += e[i];
    }
    sum += __shfl_xor(sum, 1);
    sum += __shfl_xor(sum, 2);
    float inv = 1.0f / sum;
    #pragma unroll
    for (int i = 0; i < 16; ++i) Pt[c * 16 + i][l] = e[i] * inv;
  }
  __syncthreads();

  {
    const int w = tid >> 6, l = tid & 63;
    float o[16];
    #pragma unroll
    for (int i = 0; i < 16; ++i) o[i] = 0.f;
    for (int t = 0; t < 64; ++t) {
      float p = Pt[t][l];
      #pragma unroll
      for (int d4 = 0; d4 < 4; ++d4) {
        float4 vf = *(const float4*)&Vs[t][w * 16 + d4 * 4];
        o[4 * d4]     += p * vf.x;
        o[4 * d4 + 1] += p * vf.y;
        o[4 * d4 + 2] += p * vf.z;
        o[4 * d4 + 3] += p * vf.w;
      }
    }
    float4* dst = (float4*)(ao + (((size_t)b * 16 + h) * 64 + l) * 64 + w * 16);
    #pragma unroll
    for (int d4 = 0; d4 < 4; ++d4)
      dst[d4] = make_float4(o[4 * d4], o[4 * d4 + 1], o[4 * d4 + 2], o[4 * d4 + 3]);
  }
}

// ---------------- Mt[b][c][h*64+l] = sum_d ao[b,h,l,d] * Wp[h*64+d][c]  (bf16) ----------------
__global__ void build_mt(const float* __restrict__ ao, const float* __restrict__ Wp,
                         __hip_bfloat16* __restrict__ Mt) {
  int ct = blockIdx.x;  // 0..3
  int h = blockIdx.y;   // 0..15
  int b = blockIdx.z;   // 0..3
  int c = ct * 256 + threadIdx.x;
  __shared__ float A[64][64];  // ao[l][d]
  const float* aob = ao + (((size_t)b * 16 + h) * 64) * 64;
  for (int i = threadIdx.x; i < 4096; i += 256) A[i >> 6][i & 63] = aob[i];
  __syncthreads();
  for (int lc = 0; lc < 4; ++lc) {
    float acc[16];
    #pragma unroll
    for (int li = 0; li < 16; ++li) acc[li] = 0.f;
    for (int d = 0; d < 64; ++d) {
      float wv = Wp[(size_t)(h * 64 + d) * 1024 + c];
      #pragma unroll
      for (int li = 0; li < 16; ++li) acc[li] += A[lc * 16 + li][d] * wv;
    }
    size_t base = ((size_t)b * 1024 + c) * 1024 + h * 64 + lc * 16;
    #pragma unroll
    for (int li = 0; li < 16; ++li) Mt[base + li] = __float2bfloat16(acc[li]);
  }
}

extern "C" void kernel_launch(void* const* d_in, const int* in_sizes, int n_in,
                              void* d_out, int out_size, void* d_ws, size_t ws_size,
                              hipStream_t stream) {
  const float* x  = (const float*)d_in[0];
  const float* lq = (const float*)d_in[1];
  const float* Wk = (const float*)d_in[2];
  const float* Wv = (const float*)d_in[3];
  const float* Wg = (const float*)d_in[4];
  const float* Wp = (const float*)d_in[5];
  float* out = (float*)d_out;

  // workspace layout (bytes)
  char* w = (char*)d_ws;
  __hip_bfloat16* xb   = (__hip_bfloat16*)(w);              // 33,554,432
  __hip_bfloat16* G    = (__hip_bfloat16*)(w + 33554432);   // 33,554,432
  __hip_bfloat16* WgT  = (__hip_bfloat16*)(w + 67108864);   // 2,097,152
  __hip_bfloat16* WkvT = (__hip_bfloat16*)(w + 69206016);   // 4,194,304
  float* kvtmp         = (float*)(w + 73400320);            // 4,194,304
  float* ao            = (float*)(w + 77594624);            // 1,048,576
  __hip_bfloat16* Mt   = (__hip_bfloat16*)(w + 78643200);   // 8,388,608

  // x->bf16 + 3 weight transposes, one launch
  prep_kernel<<<5120, 256, 0, stream>>>(x, xb, Wg, Wk, Wv, WgT, WkvT, WkvT + 1024 * 1024);

  // gates: G = softmax_groups(x @ Wg), bf16 [16384,1024] -- A-arm: depth-3 counted-vmcnt
  pipe256<1><<<dim3(64, 4, 1), 512, 0, stream>>>(xb, WgT, G, 1024, 1024, 0LL, 0LL, 0LL);

  // k,v for t<128 (only t<64 used): kvtmp[b][t][0:1024]=k, [1024:2048]=v (fp32)
  gemm_bt<<<dim3(1, 16, 4), 256, 0, stream>>>(xb, WkvT, kvtmp, 1024, 2048,
                                              4096LL * 1024, 0LL, 128LL * 2048);

  attn_kernel<<<dim3(16, 4), 256, 0, stream>>>(kvtmp, lq, ao);

  build_mt<<<dim3(4, 16, 4), 256, 0, stream>>>(ao, Wp, Mt);

  // out[b] = G[b] @ Mt[b]^T (fp32 out) -- B-arm (control): 256^2 2-phase
  gemm256<0><<<dim3(16, 4, 4), 512, 0, stream>>>(G, Mt, out, 1024, 1024,
                                                 4096LL * 1024, 1024LL * 1024, 4096LL * 1024);
}

// Round 8
// 173.773 us; speedup vs baseline: 1.0432x; 1.0432x over previous
//
#include <hip/hip_runtime.h>
#include <hip/hip_bf16.h>

// MultiLatentAttention on MI355X.
// causal mask t<=l with L=64 => attention only over first 64 tokens.
// out[b] = softmax_groups(x@Wg) @ M[b],  M built from attn_out and Wp.

typedef __attribute__((ext_vector_type(8))) short bf16x8;
typedef __attribute__((ext_vector_type(4))) float f32x4;
typedef __attribute__((ext_vector_type(4))) unsigned short us4;

__device__ __forceinline__ void gll16(const void* g, void* l) {
  __builtin_amdgcn_global_load_lds((const __attribute__((address_space(1))) void*)g,
                                   (__attribute__((address_space(3))) void*)l, 16, 0, 0);
}

// ---------------- prep3: 3 weight transposes fp32->bf16 ----------------
__global__ __launch_bounds__(256)
void prep3(const float* __restrict__ Wg, const float* __restrict__ Wk,
           const float* __restrict__ Wv,
           __hip_bfloat16* __restrict__ WgT, __hip_bfloat16* __restrict__ WkT,
           __hip_bfloat16* __restrict__ WvT) {
  const int bid = blockIdx.x, tid = threadIdx.x;
  const int z = bid >> 10, rem = bid & 1023;
  const float* W = (z == 0) ? Wg : ((z == 1) ? Wk : Wv);
  __hip_bfloat16* Wt = (z == 0) ? WgT : ((z == 1) ? WkT : WvT);
  __shared__ float tile[32][33];
  const int bx = (rem & 31) * 32, by = (rem >> 5) * 32;
  const int tx = tid & 31, ty = tid >> 5;  // 32x8
  #pragma unroll
  for (int j = 0; j < 32; j += 8)
    tile[ty + j][tx] = W[(size_t)(by + ty + j) * 1024 + bx + tx];
  __syncthreads();
  #pragma unroll
  for (int j = 0; j < 32; j += 8)
    Wt[(size_t)(bx + ty + j) * 1024 + by + tx] = __float2bfloat16(tile[tx][ty + j]);
}

// ---------------- gates GEMM: 256x256 2-phase, A register-staged from fp32 x ----------------
// Proven gemm256 structure (~49us); A-path replaced by T14 split: issue 8 float4 +
// B gll16 early -> compute(cur) -> cvt+ds_write(next) -> barrier (compiler emits the
// counted vmcnt for the float4 uses; barrier drains B's gll16). Same XOR swizzle
// (slot ^= row&7) pre-applied on the GLOBAL source for both A and B; reads unchanged.
// Epilogue: per-64-column-group softmax, bf16 store.
__global__ __launch_bounds__(512)
void gemm_gates(const float* __restrict__ X, const __hip_bfloat16* __restrict__ Bt,
                __hip_bfloat16* __restrict__ G) {
  __shared__ __align__(16) unsigned short SA[2][256 * 64];
  __shared__ __align__(16) unsigned short SB[2][256 * 64];
  const int tid = threadIdx.x;
  const int lane = tid & 63;
  const int w = tid >> 6;            // wave 0..7
  const int wm = w >> 2, wn = w & 3; // 2x4 wave grid; per-wave out = 128x64
  const int lr = lane & 15, lk = lane >> 4;
  const int m0 = blockIdx.x * 256, n0 = blockIdx.y * 256;
  const int K = 1024;

  f32x4 acc[8][4] = {};
  float4 av[8];

  auto loadA = [&](int kt) {
    #pragma unroll
    for (int r = 0; r < 4; ++r) {
      int c = r * 512 + tid;          // chunk: row=c>>3, slot=c&7
      int row = c >> 3, s = c & 7;
      int gs = s ^ (row & 7);         // pre-swizzled global slot
      const float* src = X + (size_t)(m0 + row) * K + kt + gs * 8;
      av[2 * r]     = *(const float4*)src;
      av[2 * r + 1] = *(const float4*)(src + 4);
    }
  };
  auto writeA = [&](int bsel) {
    #pragma unroll
    for (int r = 0; r < 4; ++r) {
      int c = r * 512 + tid;
      union { __hip_bfloat16 h[8]; bf16x8 v; } p;
      const float* f = (const float*)&av[2 * r];
      #pragma unroll
      for (int e = 0; e < 8; ++e) p.h[e] = __float2bfloat16(f[e]);
      *(bf16x8*)((char*)&SA[bsel][0] + c * 16) = p.v;
    }
  };
  auto stageB = [&](int bsel, int kt) {
    #pragma unroll
    for (int r = 0; r < 4; ++r) {
      int c = r * 512 + tid;
      int row = c >> 3, s = c & 7;
      int gch = s ^ (row & 7);
      gll16(Bt + (size_t)(n0 + row) * K + kt + gch * 8, (char*)&SB[bsel][0] + c * 16);
    }
  };

  // prologue
  loadA(0);
  stageB(0, 0);
  writeA(0);
  __syncthreads();

  int buf = 0;
  for (int t = 0; t < 16; ++t) {
    if (t + 1 < 16) { loadA((t + 1) << 6); stageB(buf ^ 1, (t + 1) << 6); }

    bf16x8 bfr[2][4];
    #pragma unroll
    for (int kk = 0; kk < 2; ++kk)
      #pragma unroll
      for (int ni = 0; ni < 4; ++ni) {
        int row = wn * 64 + ni * 16 + lr;
        int ch = (kk * 4 + lk) ^ (row & 7);
        bfr[kk][ni] = *(const bf16x8*)&SB[buf][row * 64 + ch * 8];
      }
    #pragma unroll
    for (int mi = 0; mi < 8; ++mi) {
      int row = wm * 128 + mi * 16 + lr;
      int ch0 = lk ^ (row & 7);
      int ch1 = (4 + lk) ^ (row & 7);
      bf16x8 a0 = *(const bf16x8*)&SA[buf][row * 64 + ch0 * 8];
      bf16x8 a1 = *(const bf16x8*)&SA[buf][row * 64 + ch1 * 8];
      #pragma unroll
      for (int ni = 0; ni < 4; ++ni)
        acc[mi][ni] = __builtin_amdgcn_mfma_f32_16x16x32_bf16(a0, bfr[0][ni], acc[mi][ni], 0, 0, 0);
      #pragma unroll
      for (int ni = 0; ni < 4; ++ni)
        acc[mi][ni] = __builtin_amdgcn_mfma_f32_16x16x32_bf16(a1, bfr[1][ni], acc[mi][ni], 0, 0, 0);
    }

    if (t + 1 < 16) writeA(buf ^ 1);   // vmcnt-waits av, ds_writes next buffer
    __syncthreads();
    buf ^= 1;
  }

  // Each wave's 64 columns = one softmax group (head h, l=0..63).
  #pragma unroll
  for (int mi = 0; mi < 8; ++mi) {
    #pragma unroll
    for (int jj = 0; jj < 4; ++jj) {
      float mx = -3.0e38f;
      #pragma unroll
      for (int ni = 0; ni < 4; ++ni) mx = fmaxf(mx, acc[mi][ni][jj]);
      mx = fmaxf(mx, __shfl_xor(mx, 1));
      mx = fmaxf(mx, __shfl_xor(mx, 2));
      mx = fmaxf(mx, __shfl_xor(mx, 4));
      mx = fmaxf(mx, __shfl_xor(mx, 8));
      float e[4];
      float s = 0.f;
      #pragma unroll
      for (int ni = 0; ni < 4; ++ni) { e[ni] = __expf(acc[mi][ni][jj] - mx); s += e[ni]; }
      s += __shfl_xor(s, 1);
      s += __shfl_xor(s, 2);
      s += __shfl_xor(s, 4);
      s += __shfl_xor(s, 8);
      float inv = 1.0f / s;
      int r = m0 + wm * 128 + mi * 16 + lk * 4 + jj;
      #pragma unroll
      for (int ni = 0; ni < 4; ++ni)
        G[(size_t)r * 1024 + n0 + wn * 64 + ni * 16 + lr] = __float2bfloat16(e[ni] * inv);
    }
  }
}

// ---------------- 256x256 2-phase pipelined bf16 GEMM (proven ~49us) — out projection --------
__global__ __launch_bounds__(512, 2)
void gemm256o(const __hip_bfloat16* __restrict__ A, const __hip_bfloat16* __restrict__ Bt,
              float* __restrict__ Cv, int K, int ldc,
              long long astride, long long bstride, long long cstride) {
  __shared__ __align__(16) unsigned short SA[2][256 * 64];
  __shared__ __align__(16) unsigned short SB[2][256 * 64];
  const int tid = threadIdx.x;
  const int lane = tid & 63;
  const int w = tid >> 6;
  const int wm = w >> 2, wn = w & 3;
  const int lr = lane & 15, lk = lane >> 4;
  const int m0 = blockIdx.x * 256, n0 = blockIdx.y * 256;
  const long long b = blockIdx.z;
  const __hip_bfloat16* Ab = A + b * astride;
  const __hip_bfloat16* Bb = Bt + b * bstride;

  f32x4 acc[8][4] = {};

  const int NT = K >> 6;
  int buf = 0;

  auto STAGE = [&](int bsel, int kt) {
    #pragma unroll
    for (int r = 0; r < 4; ++r) {
      int c = r * 512 + tid;
      int row = c >> 3, slot = c & 7;
      int gch = slot ^ (row & 7);
      gll16(Ab + (size_t)(m0 + row) * K + kt + gch * 8, (char*)&SA[bsel][0] + c * 16);
      gll16(Bb + (size_t)(n0 + row) * K + kt + gch * 8, (char*)&SB[bsel][0] + c * 16);
    }
  };

  STAGE(0, 0);
  __syncthreads();

  for (int t = 0; t < NT; ++t) {
    if (t + 1 < NT) STAGE(buf ^ 1, (t + 1) << 6);

    bf16x8 bfr[2][4];
    #pragma unroll
    for (int kk = 0; kk < 2; ++kk)
      #pragma unroll
      for (int ni = 0; ni < 4; ++ni) {
        int row = wn * 64 + ni * 16 + lr;
        int ch = (kk * 4 + lk) ^ (row & 7);
        bfr[kk][ni] = *(const bf16x8*)&SB[buf][row * 64 + ch * 8];
      }
    #pragma unroll
    for (int mi = 0; mi < 8; ++mi) {
      int row = wm * 128 + mi * 16 + lr;
      int ch0 = lk ^ (row & 7);
      int ch1 = (4 + lk) ^ (row & 7);
      bf16x8 a0 = *(const bf16x8*)&SA[buf][row * 64 + ch0 * 8];
      bf16x8 a1 = *(const bf16x8*)&SA[buf][row * 64 + ch1 * 8];
      #pragma unroll
      for (int ni = 0; ni < 4; ++ni)
        acc[mi][ni] = __builtin_amdgcn_mfma_f32_16x16x32_bf16(a0, bfr[0][ni], acc[mi][ni], 0, 0, 0);
      #pragma unroll
      for (int ni = 0; ni < 4; ++ni)
        acc[mi][ni] = __builtin_amdgcn_mfma_f32_16x16x32_bf16(a1, bfr[1][ni], acc[mi][ni], 0, 0, 0);
    }
    __syncthreads();
    buf ^= 1;
  }

  float* C = Cv + b * cstride;
  #pragma unroll
  for (int mi = 0; mi < 8; ++mi) {
    int r = m0 + wm * 128 + mi * 16 + lk * 4;
    #pragma unroll
    for (int ni = 0; ni < 4; ++ni) {
      int c = n0 + wn * 64 + ni * 16 + lr;
      #pragma unroll
      for (int jj = 0; jj < 4; ++jj)
        C[(size_t)(r + jj) * ldc + c] = acc[mi][ni][jj];
    }
  }
}

// ---------------- kv projection: kvtmp[256][2048], rows stacked (b*64+t), A from fp32 x ------
// 128x128 tile, BK=32, 4 waves. A register-staged (fp32 -> bf16), B gll16 from WkvT.
__global__ __launch_bounds__(256)
void gemm_kv(const float* __restrict__ X, const __hip_bfloat16* __restrict__ Bt,
             float* __restrict__ C) {
  __shared__ __align__(16) unsigned short As[128 * 32];
  __shared__ __align__(16) unsigned short Bs[128 * 32];
  const int tid = threadIdx.x;
  const int lane = tid & 63;
  const int w = tid >> 6;
  const int wm = w >> 1, wn = w & 1;
  const int lr = lane & 15, lk = lane >> 4;
  const int m0 = blockIdx.x * 128, n0 = blockIdx.y * 128;
  const int K = 1024;

  f32x4 acc[4][4] = {};

  for (int kt = 0; kt < K; kt += 32) {
    __syncthreads();  // readers done (write-after-read)
    float4 av[4];
    #pragma unroll
    for (int r = 0; r < 2; ++r) {
      int c = r * 256 + tid;          // chunk: row=c>>2, slot=c&3 (no swizzle)
      int row = c >> 2, s = c & 3;
      int rg = m0 + row;              // stacked row -> (b,t)
      const float* src = X + ((size_t)(rg >> 6) * 4096 + (rg & 63)) * 1024 + kt + s * 8;
      av[2 * r]     = *(const float4*)src;
      av[2 * r + 1] = *(const float4*)(src + 4);
    }
    #pragma unroll
    for (int r = 0; r < 2; ++r) {
      int c = r * 256 + tid;
      int row = c >> 2, s = c & 3;
      gll16(Bt + (size_t)(n0 + row) * K + kt + s * 8, (char*)Bs + c * 16);
    }
    #pragma unroll
    for (int r = 0; r < 2; ++r) {
      int c = r * 256 + tid;
      union { __hip_bfloat16 h[8]; bf16x8 v; } p;
      const float* f = (const float*)&av[2 * r];
      #pragma unroll
      for (int e = 0; e < 8; ++e) p.h[e] = __float2bfloat16(f[e]);
      *(bf16x8*)((char*)As + c * 16) = p.v;
    }
    __syncthreads();  // drains B gll16 + A ds_writes

    bf16x8 af[4], bf[4];
    #pragma unroll
    for (int mi = 0; mi < 4; ++mi)
      af[mi] = *(const bf16x8*)&As[(wm * 64 + mi * 16 + lr) * 32 + lk * 8];
    #pragma unroll
    for (int ni = 0; ni < 4; ++ni)
      bf[ni] = *(const bf16x8*)&Bs[(wn * 64 + ni * 16 + lr) * 32 + lk * 8];
    #pragma unroll
    for (int mi = 0; mi < 4; ++mi)
      #pragma unroll
      for (int ni = 0; ni < 4; ++ni)
        acc[mi][ni] = __builtin_amdgcn_mfma_f32_16x16x32_bf16(af[mi], bf[ni], acc[mi][ni], 0, 0, 0);
  }

  #pragma unroll
  for (int mi = 0; mi < 4; ++mi) {
    int r = m0 + wm * 64 + mi * 16 + lk * 4;
    #pragma unroll
    for (int ni = 0; ni < 4; ++ni) {
      int c = n0 + wn * 64 + ni * 16 + lr;
      #pragma unroll
      for (int jj = 0; jj < 4; ++jj)
        C[(size_t)(r + jj) * 2048 + c] = acc[mi][ni][jj];
    }
  }
}

// ---------------- attn (RoPE fused) + Mt build, merged: grid (ct=4, h=16, b=4) ----------------
// Each block redoes the tiny 64x64 attention for (b,h) (ao kept in LDS), then computes
// its ct-quarter of Mt[b][c][h*64+l] = sum_d ao[l,d] * Wp[h*64+d][c].
__global__ __launch_bounds__(256)
void attn_mt(const float* __restrict__ kv, const float* __restrict__ lq,
             const float* __restrict__ Wp, __hip_bfloat16* __restrict__ Mt) {
  const int ct = blockIdx.x, h = blockIdx.y, b = blockIdx.z;
  __shared__ float Ks[64][64];
  __shared__ float Vs[64][64];
  __shared__ float S[64][65];   // scores, then reused as ao[l][d]
  __shared__ float Pt[64][65];  // Pt[t][l]
  const int tid = threadIdx.x;
  const float* kb = kv + (size_t)(b * 64) * 2048 + h * 64;  // stacked rows
  const float* vb = kb + 1024;

  {
    int r = tid >> 4;            // 0..15
    int c4 = (tid & 15) * 4;     // head-dim col (pairs i0=c4/2, i0+1)
    int i0 = c4 >> 1;
    float inv0 = exp2f(-13.287712379549449f * ((float)i0 * (1.0f / 32.0f)));
    float inv1 = exp2f(-13.287712379549449f * ((float)(i0 + 1) * (1.0f / 32.0f)));
    #pragma unroll
    for (int j = 0; j < 4; ++j) {
      int row = j * 16 + r;      // t
      float4 kf = *(const float4*)&kb[(size_t)row * 2048 + c4];
      float a0 = (float)row * inv0, a1 = (float)row * inv1;
      float s0 = sinf(a0), c0 = cosf(a0), s1 = sinf(a1), c1 = cosf(a1);
      *(float4*)&Ks[row][c4] = make_float4(kf.x * c0 - kf.y * s0, kf.x * s0 + kf.y * c0,
                                           kf.z * c1 - kf.w * s1, kf.z * s1 + kf.w * c1);
      *(float4*)&Vs[row][c4] = *(const float4*)&vb[(size_t)row * 2048 + c4];
    }
  }
  __syncthreads();

  // scores: thread = (l = lane, t-chunk = wave)
  {
    const int w = tid >> 6, l = tid & 63;
    float q[64];
    const float4* lq4 = (const float4*)(lq + ((size_t)l * 16 + h) * 64);
    #pragma unroll
    for (int i = 0; i < 16; ++i) {
      float4 f = lq4[i];
      q[4 * i] = f.x; q[4 * i + 1] = f.y; q[4 * i + 2] = f.z; q[4 * i + 3] = f.w;
    }
    #pragma unroll
    for (int tl = 0; tl < 16; ++tl) {
      int t = w * 16 + tl;
      float a = 0.f;
      #pragma unroll
      for (int d4 = 0; d4 < 16; ++d4) {
        float4 kf = *(const float4*)&Ks[t][d4 * 4];
        a += q[4 * d4] * kf.x + q[4 * d4 + 1] * kf.y + q[4 * d4 + 2] * kf.z + q[4 * d4 + 3] * kf.w;
      }
      S[l][t] = a * 0.125f;
    }
  }
  __syncthreads();

  // softmax: thread = (l = tid>>2, c = tid&3), causal t<=l
  {
    const int l = tid >> 2, c = tid & 3;
    float sv[16];
    float mx = -3.0e38f;
    #pragma unroll
    for (int i = 0; i < 16; ++i) {
      int t = c * 16 + i;
      sv[i] = S[l][t];
      if (t <= l) mx = fmaxf(mx, sv[i]);
    }
    mx = fmaxf(mx, __shfl_xor(mx, 1));
    mx = fmaxf(mx, __shfl_xor(mx, 2));
    float sum = 0.f;
    float e[16];
    #pragma unroll
    for (int i = 0; i < 16; ++i) {
      int t = c * 16 + i;
      e[i] = (t <= l) ? __expf(sv[i] - mx) : 0.f;
      sum += e[i];
    }
    sum += __shfl_xor(sum, 1);
    sum += __shfl_xor(sum, 2);
    float inv = 1.0f / sum;
    #pragma unroll
    for (int i = 0; i < 16; ++i) Pt[c * 16 + i][l] = e[i] * inv;
  }
  __syncthreads();

  // PV: thread = (l = lane, d-chunk = wave); ao -> S[l][d]
  {
    const int w = tid >> 6, l = tid & 63;
    float o[16];
    #pragma unroll
    for (int i = 0; i < 16; ++i) o[i] = 0.f;
    for (int t = 0; t < 64; ++t) {
      float p = Pt[t][l];
      #pragma unroll
      for (int d4 = 0; d4 < 4; ++d4) {
        float4 vf = *(const float4*)&Vs[t][w * 16 + d4 * 4];
        o[4 * d4]     += p * vf.x;
        o[4 * d4 + 1] += p * vf.y;
        o[4 * d4 + 2] += p * vf.z;
        o[4 * d4 + 3] += p * vf.w;
      }
    }
    #pragma unroll
    for (int i = 0; i < 16; ++i) S[l][w * 16 + i] = o[i];
  }
  __syncthreads();

  // Mt quarter: c = ct*256 + tid
  {
    const int c = ct * 256 + tid;
    for (int lc = 0; lc < 4; ++lc) {
      float a2[16];
      #pragma unroll
      for (int li = 0; li < 16; ++li) a2[li] = 0.f;
      for (int d = 0; d < 64; ++d) {
        float wv = Wp[(size_t)(h * 64 + d) * 1024 + c];
        #pragma unroll
        for (int li = 0; li < 16; ++li) a2[li] += S[lc * 16 + li][d] * wv;
      }
      size_t base = ((size_t)b * 1024 + c) * 1024 + h * 64 + lc * 16;
      #pragma unroll
      for (int li = 0; li < 16; ++li) Mt[base + li] = __float2bfloat16(a2[li]);
    }
  }
}

extern "C" void kernel_launch(void* const* d_in, const int* in_sizes, int n_in,
                              void* d_out, int out_size, void* d_ws, size_t ws_size,
                              hipStream_t stream) {
  const float* x  = (const float*)d_in[0];
  const float* lq = (const float*)d_in[1];
  const float* Wk = (const float*)d_in[2];
  const float* Wv = (const float*)d_in[3];
  const float* Wg = (const float*)d_in[4];
  const float* Wp = (const float*)d_in[5];
  float* out = (float*)d_out;

  // workspace layout (bytes)
  char* w = (char*)d_ws;
  __hip_bfloat16* G    = (__hip_bfloat16*)(w);              // 33,554,432
  __hip_bfloat16* WgT  = (__hip_bfloat16*)(w + 33554432);   // 2,097,152
  __hip_bfloat16* WkvT = (__hip_bfloat16*)(w + 35651584);   // 4,194,304
  float* kvtmp         = (float*)(w + 39845888);            // 256*2048*4 = 2,097,152
  __hip_bfloat16* Mt   = (__hip_bfloat16*)(w + 41943040);   // 8,388,608
  // total 50,331,648 B

  // 3 weight transposes
  prep3<<<3072, 256, 0, stream>>>(Wg, Wk, Wv, WgT, WkvT, WkvT + 1024 * 1024);

  // gates: G = softmax_groups(x @ Wg), bf16 [16384,1024]; A staged from fp32 x
  gemm_gates<<<dim3(64, 4), 512, 0, stream>>>(x, WgT, G);

  // k,v for stacked rows (b*64+t), t<64: kvtmp[256][2048] fp32
  gemm_kv<<<dim3(2, 16), 256, 0, stream>>>(x, WkvT, kvtmp);

  // attention + Mt build (merged)
  attn_mt<<<dim3(4, 16, 4), 256, 0, stream>>>(kvtmp, lq, Wp, Mt);

  // out[b] = G[b] @ Mt[b]^T (fp32 out)
  gemm256o<<<dim3(16, 4, 4), 512, 0, stream>>>(G, Mt, out, 1024, 1024,
                                               4096LL * 1024, 1024LL * 1024, 4096LL * 1024);
}

// Round 9
// 159.720 us; speedup vs baseline: 1.1350x; 1.0880x over previous
//
#include <hip/hip_runtime.h>
#include <hip/hip_bf16.h>

// MultiLatentAttention on MI355X.
// causal mask t<=l with L=64 => attention only over first 64 tokens.
// out[b] = softmax_groups(x@Wg) @ M[b],  M built from attn_out and Wp.

typedef __attribute__((ext_vector_type(8))) short bf16x8;
typedef __attribute__((ext_vector_type(4))) float f32x4;
typedef __attribute__((ext_vector_type(4))) unsigned short us4;

__device__ __forceinline__ void gll16(const void* g, void* l) {
  __builtin_amdgcn_global_load_lds((const __attribute__((address_space(1))) void*)g,
                                   (__attribute__((address_space(3))) void*)l, 16, 0, 0);
}

// ---------------- prep: x->bf16 (blocks 0..2047) + 3 weight transposes (blocks 2048..5119) ----
__global__ __launch_bounds__(256)
void prep_kernel(const float* __restrict__ x, __hip_bfloat16* __restrict__ xb,
                 const float* __restrict__ Wg, const float* __restrict__ Wk,
                 const float* __restrict__ Wv,
                 __hip_bfloat16* __restrict__ WgT, __hip_bfloat16* __restrict__ WkT,
                 __hip_bfloat16* __restrict__ WvT) {
  const int bid = blockIdx.x, tid = threadIdx.x;
  if (bid < 2048) {
    const int stride = 2048 * 256;
    for (int i = bid * 256 + tid; i < 4194304; i += stride) {
      float4 f = reinterpret_cast<const float4*>(x)[i];
      union { __hip_bfloat16 h[4]; us4 v; } u;
      u.h[0] = __float2bfloat16(f.x);
      u.h[1] = __float2bfloat16(f.y);
      u.h[2] = __float2bfloat16(f.z);
      u.h[3] = __float2bfloat16(f.w);
      reinterpret_cast<us4*>(xb)[i] = u.v;
    }
  } else {
    const int t = bid - 2048;
    const int z = t >> 10, rem = t & 1023;
    const float* W = (z == 0) ? Wg : ((z == 1) ? Wk : Wv);
    __hip_bfloat16* Wt = (z == 0) ? WgT : ((z == 1) ? WkT : WvT);
    __shared__ float tile[32][33];
    const int bx = (rem & 31) * 32, by = (rem >> 5) * 32;
    const int tx = tid & 31, ty = tid >> 5;  // 32x8
    #pragma unroll
    for (int j = 0; j < 32; j += 8)
      tile[ty + j][tx] = W[(size_t)(by + ty + j) * 1024 + bx + tx];
    __syncthreads();
    #pragma unroll
    for (int j = 0; j < 32; j += 8)
      Wt[(size_t)(bx + ty + j) * 1024 + by + tx] = __float2bfloat16(tile[tx][ty + j]);
  }
}

// ---------------- 256x256 2-phase pipelined bf16 GEMM (proven ~49us) ----------------
// 8 waves (2Mx4N), BK=64, double-buffered 128KiB LDS. LDS swizzle: 16B-chunk ^= (row&7),
// pre-swizzled on the GLOBAL source (gll16 dest linear), applied on fragment reads.
// EPI=0: fp32 store. EPI=1: per-64-column-group softmax, bf16 store (gates).
template <int EPI>
__global__ __launch_bounds__(512, 2)
void gemm256(const __hip_bfloat16* __restrict__ A, const __hip_bfloat16* __restrict__ Bt,
             void* __restrict__ Cv, int K, int ldc,
             long long astride, long long bstride, long long cstride) {
  __shared__ __align__(16) unsigned short SA[2][256 * 64];
  __shared__ __align__(16) unsigned short SB[2][256 * 64];
  const int tid = threadIdx.x;
  const int lane = tid & 63;
  const int w = tid >> 6;            // wave 0..7
  const int wm = w >> 2, wn = w & 3; // 2x4 wave grid; per-wave out = 128x64
  const int lr = lane & 15, lk = lane >> 4;
  const int m0 = blockIdx.x * 256, n0 = blockIdx.y * 256;
  const long long b = blockIdx.z;
  const __hip_bfloat16* Ab = A + b * astride;
  const __hip_bfloat16* Bb = Bt + b * bstride;

  f32x4 acc[8][4] = {};

  const int NT = K >> 6;
  int buf = 0;

  auto STAGE = [&](int bsel, int kt) {
    #pragma unroll
    for (int r = 0; r < 4; ++r) {
      int c = r * 512 + tid;          // chunk 0..2047: row=c>>3, slot=c&7
      int row = c >> 3, slot = c & 7;
      int gch = slot ^ (row & 7);     // pre-swizzled global chunk
      gll16(Ab + (size_t)(m0 + row) * K + kt + gch * 8, (char*)&SA[bsel][0] + c * 16);
      gll16(Bb + (size_t)(n0 + row) * K + kt + gch * 8, (char*)&SB[bsel][0] + c * 16);
    }
  };

  STAGE(0, 0);
  __syncthreads();

  for (int t = 0; t < NT; ++t) {
    if (t + 1 < NT) STAGE(buf ^ 1, (t + 1) << 6);

    bf16x8 bfr[2][4];
    #pragma unroll
    for (int kk = 0; kk < 2; ++kk)
      #pragma unroll
      for (int ni = 0; ni < 4; ++ni) {
        int row = wn * 64 + ni * 16 + lr;
        int ch = (kk * 4 + lk) ^ (row & 7);
        bfr[kk][ni] = *(const bf16x8*)&SB[buf][row * 64 + ch * 8];
      }
    #pragma unroll
    for (int mi = 0; mi < 8; ++mi) {
      int row = wm * 128 + mi * 16 + lr;
      int ch0 = lk ^ (row & 7);
      int ch1 = (4 + lk) ^ (row & 7);
      bf16x8 a0 = *(const bf16x8*)&SA[buf][row * 64 + ch0 * 8];
      bf16x8 a1 = *(const bf16x8*)&SA[buf][row * 64 + ch1 * 8];
      #pragma unroll
      for (int ni = 0; ni < 4; ++ni)
        acc[mi][ni] = __builtin_amdgcn_mfma_f32_16x16x32_bf16(a0, bfr[0][ni], acc[mi][ni], 0, 0, 0);
      #pragma unroll
      for (int ni = 0; ni < 4; ++ni)
        acc[mi][ni] = __builtin_amdgcn_mfma_f32_16x16x32_bf16(a1, bfr[1][ni], acc[mi][ni], 0, 0, 0);
    }
    __syncthreads();
    buf ^= 1;
  }

  if (EPI == 0) {
    float* C = (float*)Cv + b * cstride;
    #pragma unroll
    for (int mi = 0; mi < 8; ++mi) {
      int r = m0 + wm * 128 + mi * 16 + lk * 4;
      #pragma unroll
      for (int ni = 0; ni < 4; ++ni) {
        int c = n0 + wn * 64 + ni * 16 + lr;
        #pragma unroll
        for (int jj = 0; jj < 4; ++jj)
          C[(size_t)(r + jj) * ldc + c] = acc[mi][ni][jj];
      }
    }
  } else {
    // Each wave's 64 columns = one softmax group (head h, l=0..63).
    __hip_bfloat16* C = (__hip_bfloat16*)Cv + b * cstride;
    #pragma unroll
    for (int mi = 0; mi < 8; ++mi) {
      #pragma unroll
      for (int jj = 0; jj < 4; ++jj) {
        float mx = -3.0e38f;
        #pragma unroll
        for (int ni = 0; ni < 4; ++ni) mx = fmaxf(mx, acc[mi][ni][jj]);
        mx = fmaxf(mx, __shfl_xor(mx, 1));
        mx = fmaxf(mx, __shfl_xor(mx, 2));
        mx = fmaxf(mx, __shfl_xor(mx, 4));
        mx = fmaxf(mx, __shfl_xor(mx, 8));
        float e[4];
        float s = 0.f;
        #pragma unroll
        for (int ni = 0; ni < 4; ++ni) { e[ni] = __expf(acc[mi][ni][jj] - mx); s += e[ni]; }
        s += __shfl_xor(s, 1);
        s += __shfl_xor(s, 2);
        s += __shfl_xor(s, 4);
        s += __shfl_xor(s, 8);
        float inv = 1.0f / s;
        int r = m0 + wm * 128 + mi * 16 + lk * 4 + jj;
        #pragma unroll
        for (int ni = 0; ni < 4; ++ni)
          C[(size_t)r * ldc + n0 + wn * 64 + ni * 16 + lr] = __float2bfloat16(e[ni] * inv);
      }
    }
  }
}

// ---------------- kv projection, split-K=8: kvp[ks][256][2048] fp32 partials ----------------
// Stacked rows (b*64+t, t<64). 128x128 tile, BK=32, 4 waves, 4 K-iters per block.
// Grid (2, 16, 8) = 256 blocks -> full CU fill.
__global__ __launch_bounds__(256)
void gemm_kv(const __hip_bfloat16* __restrict__ A, const __hip_bfloat16* __restrict__ Bt,
             float* __restrict__ kvp) {
  __shared__ __align__(16) unsigned short As[128 * 32];
  __shared__ __align__(16) unsigned short Bs[128 * 32];
  const int tid = threadIdx.x;
  const int lane = tid & 63;
  const int w = tid >> 6;
  const int wm = w >> 1, wn = w & 1;
  const int lr = lane & 15, lk = lane >> 4;
  const int m0 = blockIdx.x * 128, n0 = blockIdx.y * 128;
  const int ks = blockIdx.z;
  const int K = 1024;

  f32x4 acc[4][4] = {};
  const int r0 = tid >> 2;
  const int c8 = (tid & 3) * 8;

  // stacked row -> global x row
  auto xrow = [&](int rg) { return (size_t)(rg >> 6) * 4096 + (rg & 63); };

  for (int ki = 0; ki < 4; ++ki) {
    int kt = ks * 128 + ki * 32;
    __syncthreads();
    gll16(A + xrow(m0 + r0) * K + kt + c8,      (char*)As + (w * 64) * 16);
    gll16(Bt + (size_t)(n0 + r0) * K + kt + c8, (char*)Bs + (w * 64) * 16);
    gll16(A + xrow(m0 + 64 + r0) * K + kt + c8,      (char*)As + (256 + w * 64) * 16);
    gll16(Bt + (size_t)(n0 + 64 + r0) * K + kt + c8, (char*)Bs + (256 + w * 64) * 16);
    __syncthreads();

    bf16x8 af[4], bf[4];
    #pragma unroll
    for (int mi = 0; mi < 4; ++mi)
      af[mi] = *(const bf16x8*)&As[(wm * 64 + mi * 16 + lr) * 32 + lk * 8];
    #pragma unroll
    for (int ni = 0; ni < 4; ++ni)
      bf[ni] = *(const bf16x8*)&Bs[(wn * 64 + ni * 16 + lr) * 32 + lk * 8];
    #pragma unroll
    for (int mi = 0; mi < 4; ++mi)
      #pragma unroll
      for (int ni = 0; ni < 4; ++ni)
        acc[mi][ni] = __builtin_amdgcn_mfma_f32_16x16x32_bf16(af[mi], bf[ni], acc[mi][ni], 0, 0, 0);
  }

  float* C = kvp + (size_t)ks * 256 * 2048;
  #pragma unroll
  for (int mi = 0; mi < 4; ++mi) {
    int r = m0 + wm * 64 + mi * 16 + lk * 4;
    #pragma unroll
    for (int ni = 0; ni < 4; ++ni) {
      int c = n0 + wn * 64 + ni * 16 + lr;
      #pragma unroll
      for (int jj = 0; jj < 4; ++jj)
        C[(size_t)(r + jj) * 2048 + c] = acc[mi][ni][jj];
    }
  }
}

// ---------------- attn (split-K sum + RoPE fused) + Mt build: grid (ct=4, h=16, b=4) --------
// Each block sums the 8 kv partials for (b,h), RoPEs K, redoes the tiny 64x64 attention
// (ao in LDS), then computes its ct-quarter of Mt[b][c][h*64+l] = sum_d ao[l,d]*Wp[h*64+d][c].
__global__ __launch_bounds__(256)
void attn_mt(const float* __restrict__ kvp, const float* __restrict__ lq,
             const float* __restrict__ Wp, __hip_bfloat16* __restrict__ Mt) {
  const int ct = blockIdx.x, h = blockIdx.y, b = blockIdx.z;
  __shared__ float Ks[64][64];
  __shared__ float Vs[64][64];
  __shared__ float S[64][65];   // scores, then reused as ao[l][d]
  __shared__ float Pt[64][65];  // Pt[t][l]
  const int tid = threadIdx.x;

  {
    int r = tid >> 4;            // 0..15
    int c4 = (tid & 15) * 4;     // head-dim col (pairs i0=c4/2, i0+1)
    int i0 = c4 >> 1;
    float inv0 = exp2f(-13.287712379549449f * ((float)i0 * (1.0f / 32.0f)));
    float inv1 = exp2f(-13.287712379549449f * ((float)(i0 + 1) * (1.0f / 32.0f)));
    #pragma unroll
    for (int j = 0; j < 4; ++j) {
      int row = j * 16 + r;      // t
      float4 kf = make_float4(0.f, 0.f, 0.f, 0.f);
      float4 vf = make_float4(0.f, 0.f, 0.f, 0.f);
      #pragma unroll
      for (int ks = 0; ks < 8; ++ks) {
        const float* base = kvp + ((size_t)ks * 256 + b * 64 + row) * 2048 + h * 64;
        float4 kp = *(const float4*)(base + c4);
        float4 vp = *(const float4*)(base + 1024 + c4);
        kf.x += kp.x; kf.y += kp.y; kf.z += kp.z; kf.w += kp.w;
        vf.x += vp.x; vf.y += vp.y; vf.z += vp.z; vf.w += vp.w;
      }
      float a0 = (float)row * inv0, a1 = (float)row * inv1;
      float s0 = sinf(a0), c0 = cosf(a0), s1 = sinf(a1), c1 = cosf(a1);
      *(float4*)&Ks[row][c4] = make_float4(kf.x * c0 - kf.y * s0, kf.x * s0 + kf.y * c0,
                                           kf.z * c1 - kf.w * s1, kf.z * s1 + kf.w * c1);
      *(float4*)&Vs[row][c4] = vf;
    }
  }
  __syncthreads();

  // scores: thread = (l = lane, t-chunk = wave)
  {
    const int w = tid >> 6, l = tid & 63;
    float q[64];
    const float4* lq4 = (const float4*)(lq + ((size_t)l * 16 + h) * 64);
    #pragma unroll
    for (int i = 0; i < 16; ++i) {
      float4 f = lq4[i];
      q[4 * i] = f.x; q[4 * i + 1] = f.y; q[4 * i + 2] = f.z; q[4 * i + 3] = f.w;
    }
    #pragma unroll
    for (int tl = 0; tl < 16; ++tl) {
      int t = w * 16 + tl;
      float a = 0.f;
      #pragma unroll
      for (int d4 = 0; d4 < 16; ++d4) {
        float4 kf = *(const float4*)&Ks[t][d4 * 4];
        a += q[4 * d4] * kf.x + q[4 * d4 + 1] * kf.y + q[4 * d4 + 2] * kf.z + q[4 * d4 + 3] * kf.w;
      }
      S[l][t] = a * 0.125f;
    }
  }
  __syncthreads();

  // softmax: thread = (l = tid>>2, c = tid&3), causal t<=l
  {
    const int l = tid >> 2, c = tid & 3;
    float sv[16];
    float mx = -3.0e38f;
    #pragma unroll
    for (int i = 0; i < 16; ++i) {
      int t = c * 16 + i;
      sv[i] = S[l][t];
      if (t <= l) mx = fmaxf(mx, sv[i]);
    }
    mx = fmaxf(mx, __shfl_xor(mx, 1));
    mx = fmaxf(mx, __shfl_xor(mx, 2));
    float sum = 0.f;
    float e[16];
    #pragma unroll
    for (int i = 0; i < 16; ++i) {
      int t = c * 16 + i;
      e[i] = (t <= l) ? __expf(sv[i] - mx) : 0.f;
      sum += e[i];
    }
    sum += __shfl_xor(sum, 1);
    sum += __shfl_xor(sum, 2);
    float inv = 1.0f / sum;
    #pragma unroll
    for (int i = 0; i < 16; ++i) Pt[c * 16 + i][l] = e[i] * inv;
  }
  __syncthreads();

  // PV: thread = (l = lane, d-chunk = wave); ao -> S[l][d]
  {
    const int w = tid >> 6, l = tid & 63;
    float o[16];
    #pragma unroll
    for (int i = 0; i < 16; ++i) o[i] = 0.f;
    for (int t = 0; t < 64; ++t) {
      float p = Pt[t][l];
      #pragma unroll
      for (int d4 = 0; d4 < 4; ++d4) {
        float4 vf = *(const float4*)&Vs[t][w * 16 + d4 * 4];
        o[4 * d4]     += p * vf.x;
        o[4 * d4 + 1] += p * vf.y;
        o[4 * d4 + 2] += p * vf.z;
        o[4 * d4 + 3] += p * vf.w;
      }
    }
    #pragma unroll
    for (int i = 0; i < 16; ++i) S[l][w * 16 + i] = o[i];
  }
  __syncthreads();

  // Mt quarter: c = ct*256 + tid
  {
    const int c = ct * 256 + tid;
    for (int lc = 0; lc < 4; ++lc) {
      float a2[16];
      #pragma unroll
      for (int li = 0; li < 16; ++li) a2[li] = 0.f;
      for (int d = 0; d < 64; ++d) {
        float wv = Wp[(size_t)(h * 64 + d) * 1024 + c];
        #pragma unroll
        for (int li = 0; li < 16; ++li) a2[li] += S[lc * 16 + li][d] * wv;
      }
      size_t base = ((size_t)b * 1024 + c) * 1024 + h * 64 + lc * 16;
      #pragma unroll
      for (int li = 0; li < 16; ++li) Mt[base + li] = __float2bfloat16(a2[li]);
    }
  }
}

extern "C" void kernel_launch(void* const* d_in, const int* in_sizes, int n_in,
                              void* d_out, int out_size, void* d_ws, size_t ws_size,
                              hipStream_t stream) {
  const float* x  = (const float*)d_in[0];
  const float* lq = (const float*)d_in[1];
  const float* Wk = (const float*)d_in[2];
  const float* Wv = (const float*)d_in[3];
  const float* Wg = (const float*)d_in[4];
  const float* Wp = (const float*)d_in[5];
  float* out = (float*)d_out;

  // workspace layout (bytes)
  char* w = (char*)d_ws;
  __hip_bfloat16* xb   = (__hip_bfloat16*)(w);              // 33,554,432
  __hip_bfloat16* G    = (__hip_bfloat16*)(w + 33554432);   // 33,554,432
  __hip_bfloat16* WgT  = (__hip_bfloat16*)(w + 67108864);   // 2,097,152
  __hip_bfloat16* WkvT = (__hip_bfloat16*)(w + 69206016);   // 4,194,304
  __hip_bfloat16* Mt   = (__hip_bfloat16*)(w + 73400320);   // 8,388,608
  // total 81,788,928 B (< proven 87MB)
  // kv partials live in d_out (16MB of its 64MB), consumed by attn_mt before
  // the final GEMM overwrites all of d_out. Deterministic.
  float* kvp = out;

  // x->bf16 + 3 weight transposes, one launch
  prep_kernel<<<5120, 256, 0, stream>>>(x, xb, Wg, Wk, Wv, WgT, WkvT, WkvT + 1024 * 1024);

  // gates: G = softmax_groups(x @ Wg), bf16 [16384,1024] (proven 2-phase, ~49us)
  gemm256<1><<<dim3(64, 4, 1), 512, 0, stream>>>(xb, WgT, G, 1024, 1024, 0LL, 0LL, 0LL);

  // k,v split-K partials: kvp[8][256][2048] fp32 (stacked rows b*64+t)
  gemm_kv<<<dim3(2, 16, 8), 256, 0, stream>>>(xb, WkvT, kvp);

  // attention (+partial sum +RoPE) + Mt build
  attn_mt<<<dim3(4, 16, 4), 256, 0, stream>>>(kvp, lq, Wp, Mt);

  // out[b] = G[b] @ Mt[b]^T (fp32 out, overwrites kvp scratch)
  gemm256<0><<<dim3(16, 4, 4), 512, 0, stream>>>(G, Mt, out, 1024, 1024,
                                                 4096LL * 1024, 1024LL * 1024, 4096LL * 1024);
}

// Round 10
// 132.344 us; speedup vs baseline: 1.3698x; 1.2068x over previous
//
#include <hip/hip_runtime.h>
#include <hip/hip_bf16.h>

// MultiLatentAttention on MI355X.
// causal mask t<=l with L=64 => attention only over first 64 tokens.
// out[b] = softmax_groups(x@Wg) @ M[b],  M built from attn_out and Wp (MFMA).

typedef __attribute__((ext_vector_type(8))) short bf16x8;
typedef __attribute__((ext_vector_type(4))) float f32x4;
typedef __attribute__((ext_vector_type(4))) unsigned short us4;
typedef __attribute__((ext_vector_type(8))) unsigned short us8;

__device__ __forceinline__ void gll16(const void* g, void* l) {
  __builtin_amdgcn_global_load_lds((const __attribute__((address_space(1))) void*)g,
                                   (__attribute__((address_space(3))) void*)l, 16, 0, 0);
}

// ---------------- prep: x->bf16 (blocks 0..2047) + 4 weight transposes (2048..6143) ----------
__global__ __launch_bounds__(256)
void prep_kernel(const float* __restrict__ x, __hip_bfloat16* __restrict__ xb,
                 const float* __restrict__ Wg, const float* __restrict__ Wk,
                 const float* __restrict__ Wv, const float* __restrict__ Wp,
                 __hip_bfloat16* __restrict__ WgT, __hip_bfloat16* __restrict__ WkT,
                 __hip_bfloat16* __restrict__ WvT, __hip_bfloat16* __restrict__ WpT) {
  const int bid = blockIdx.x, tid = threadIdx.x;
  if (bid < 2048) {
    const int stride = 2048 * 256;
    for (int i = bid * 256 + tid; i < 4194304; i += stride) {
      float4 f = reinterpret_cast<const float4*>(x)[i];
      union { __hip_bfloat16 h[4]; us4 v; } u;
      u.h[0] = __float2bfloat16(f.x);
      u.h[1] = __float2bfloat16(f.y);
      u.h[2] = __float2bfloat16(f.z);
      u.h[3] = __float2bfloat16(f.w);
      reinterpret_cast<us4*>(xb)[i] = u.v;
    }
  } else {
    const int t = bid - 2048;
    const int z = t >> 10, rem = t & 1023;
    const float* W = (z == 0) ? Wg : ((z == 1) ? Wk : ((z == 2) ? Wv : Wp));
    __hip_bfloat16* Wt = (z == 0) ? WgT : ((z == 1) ? WkT : ((z == 2) ? WvT : WpT));
    __shared__ float tile[32][33];
    const int bx = (rem & 31) * 32, by = (rem >> 5) * 32;
    const int tx = tid & 31, ty = tid >> 5;  // 32x8
    #pragma unroll
    for (int j = 0; j < 32; j += 8)
      tile[ty + j][tx] = W[(size_t)(by + ty + j) * 1024 + bx + tx];
    __syncthreads();
    #pragma unroll
    for (int j = 0; j < 32; j += 8)
      Wt[(size_t)(bx + ty + j) * 1024 + by + tx] = __float2bfloat16(tile[tx][ty + j]);
  }
}

// ---------------- 256x256 2-phase pipelined bf16 GEMM (proven ~49us) ----------------
// 8 waves (2Mx4N), BK=64, double-buffered 128KiB LDS. LDS swizzle: 16B-chunk ^= (row&7),
// pre-swizzled on the GLOBAL source (gll16 dest linear), applied on fragment reads.
// EPI=0: fp32 store. EPI=1: per-64-column-group softmax, bf16 store (gates).
template <int EPI>
__global__ __launch_bounds__(512, 2)
void gemm256(const __hip_bfloat16* __restrict__ A, const __hip_bfloat16* __restrict__ Bt,
             void* __restrict__ Cv, int K, int ldc,
             long long astride, long long bstride, long long cstride) {
  __shared__ __align__(16) unsigned short SA[2][256 * 64];
  __shared__ __align__(16) unsigned short SB[2][256 * 64];
  const int tid = threadIdx.x;
  const int lane = tid & 63;
  const int w = tid >> 6;            // wave 0..7
  const int wm = w >> 2, wn = w & 3; // 2x4 wave grid; per-wave out = 128x64
  const int lr = lane & 15, lk = lane >> 4;
  const int m0 = blockIdx.x * 256, n0 = blockIdx.y * 256;
  const long long b = blockIdx.z;
  const __hip_bfloat16* Ab = A + b * astride;
  const __hip_bfloat16* Bb = Bt + b * bstride;

  f32x4 acc[8][4] = {};

  const int NT = K >> 6;
  int buf = 0;

  auto STAGE = [&](int bsel, int kt) {
    #pragma unroll
    for (int r = 0; r < 4; ++r) {
      int c = r * 512 + tid;          // chunk 0..2047: row=c>>3, slot=c&7
      int row = c >> 3, slot = c & 7;
      int gch = slot ^ (row & 7);     // pre-swizzled global chunk
      gll16(Ab + (size_t)(m0 + row) * K + kt + gch * 8, (char*)&SA[bsel][0] + c * 16);
      gll16(Bb + (size_t)(n0 + row) * K + kt + gch * 8, (char*)&SB[bsel][0] + c * 16);
    }
  };

  STAGE(0, 0);
  __syncthreads();

  for (int t = 0; t < NT; ++t) {
    if (t + 1 < NT) STAGE(buf ^ 1, (t + 1) << 6);

    bf16x8 bfr[2][4];
    #pragma unroll
    for (int kk = 0; kk < 2; ++kk)
      #pragma unroll
      for (int ni = 0; ni < 4; ++ni) {
        int row = wn * 64 + ni * 16 + lr;
        int ch = (kk * 4 + lk) ^ (row & 7);
        bfr[kk][ni] = *(const bf16x8*)&SB[buf][row * 64 + ch * 8];
      }
    #pragma unroll
    for (int mi = 0; mi < 8; ++mi) {
      int row = wm * 128 + mi * 16 + lr;
      int ch0 = lk ^ (row & 7);
      int ch1 = (4 + lk) ^ (row & 7);
      bf16x8 a0 = *(const bf16x8*)&SA[buf][row * 64 + ch0 * 8];
      bf16x8 a1 = *(const bf16x8*)&SA[buf][row * 64 + ch1 * 8];
      #pragma unroll
      for (int ni = 0; ni < 4; ++ni)
        acc[mi][ni] = __builtin_amdgcn_mfma_f32_16x16x32_bf16(a0, bfr[0][ni], acc[mi][ni], 0, 0, 0);
      #pragma unroll
      for (int ni = 0; ni < 4; ++ni)
        acc[mi][ni] = __builtin_amdgcn_mfma_f32_16x16x32_bf16(a1, bfr[1][ni], acc[mi][ni], 0, 0, 0);
    }
    __syncthreads();
    buf ^= 1;
  }

  if (EPI == 0) {
    float* C = (float*)Cv + b * cstride;
    #pragma unroll
    for (int mi = 0; mi < 8; ++mi) {
      int r = m0 + wm * 128 + mi * 16 + lk * 4;
      #pragma unroll
      for (int ni = 0; ni < 4; ++ni) {
        int c = n0 + wn * 64 + ni * 16 + lr;
        #pragma unroll
        for (int jj = 0; jj < 4; ++jj)
          C[(size_t)(r + jj) * ldc + c] = acc[mi][ni][jj];
      }
    }
  } else {
    // Each wave's 64 columns = one softmax group (head h, l=0..63).
    __hip_bfloat16* C = (__hip_bfloat16*)Cv + b * cstride;
    #pragma unroll
    for (int mi = 0; mi < 8; ++mi) {
      #pragma unroll
      for (int jj = 0; jj < 4; ++jj) {
        float mx = -3.0e38f;
        #pragma unroll
        for (int ni = 0; ni < 4; ++ni) mx = fmaxf(mx, acc[mi][ni][jj]);
        mx = fmaxf(mx, __shfl_xor(mx, 1));
        mx = fmaxf(mx, __shfl_xor(mx, 2));
        mx = fmaxf(mx, __shfl_xor(mx, 4));
        mx = fmaxf(mx, __shfl_xor(mx, 8));
        float e[4];
        float s = 0.f;
        #pragma unroll
        for (int ni = 0; ni < 4; ++ni) { e[ni] = __expf(acc[mi][ni][jj] - mx); s += e[ni]; }
        s += __shfl_xor(s, 1);
        s += __shfl_xor(s, 2);
        s += __shfl_xor(s, 4);
        s += __shfl_xor(s, 8);
        float inv = 1.0f / s;
        int r = m0 + wm * 128 + mi * 16 + lk * 4 + jj;
        #pragma unroll
        for (int ni = 0; ni < 4; ++ni)
          C[(size_t)r * ldc + n0 + wn * 64 + ni * 16 + lr] = __float2bfloat16(e[ni] * inv);
      }
    }
  }
}

// ---------------- kv projection, split-K=8: kvp[ks][256][2048] fp32 partials ----------------
__global__ __launch_bounds__(256)
void gemm_kv(const __hip_bfloat16* __restrict__ A, const __hip_bfloat16* __restrict__ Bt,
             float* __restrict__ kvp) {
  __shared__ __align__(16) unsigned short As[128 * 32];
  __shared__ __align__(16) unsigned short Bs[128 * 32];
  const int tid = threadIdx.x;
  const int lane = tid & 63;
  const int w = tid >> 6;
  const int wm = w >> 1, wn = w & 1;
  const int lr = lane & 15, lk = lane >> 4;
  const int m0 = blockIdx.x * 128, n0 = blockIdx.y * 128;
  const int ks = blockIdx.z;
  const int K = 1024;

  f32x4 acc[4][4] = {};
  const int r0 = tid >> 2;
  const int c8 = (tid & 3) * 8;

  auto xrow = [&](int rg) { return (size_t)(rg >> 6) * 4096 + (rg & 63); };

  for (int ki = 0; ki < 4; ++ki) {
    int kt = ks * 128 + ki * 32;
    __syncthreads();
    gll16(A + xrow(m0 + r0) * K + kt + c8,      (char*)As + (w * 64) * 16);
    gll16(Bt + (size_t)(n0 + r0) * K + kt + c8, (char*)Bs + (w * 64) * 16);
    gll16(A + xrow(m0 + 64 + r0) * K + kt + c8,      (char*)As + (256 + w * 64) * 16);
    gll16(Bt + (size_t)(n0 + 64 + r0) * K + kt + c8, (char*)Bs + (256 + w * 64) * 16);
    __syncthreads();

    bf16x8 af[4], bf[4];
    #pragma unroll
    for (int mi = 0; mi < 4; ++mi)
      af[mi] = *(const bf16x8*)&As[(wm * 64 + mi * 16 + lr) * 32 + lk * 8];
    #pragma unroll
    for (int ni = 0; ni < 4; ++ni)
      bf[ni] = *(const bf16x8*)&Bs[(wn * 64 + ni * 16 + lr) * 32 + lk * 8];
    #pragma unroll
    for (int mi = 0; mi < 4; ++mi)
      #pragma unroll
      for (int ni = 0; ni < 4; ++ni)
        acc[mi][ni] = __builtin_amdgcn_mfma_f32_16x16x32_bf16(af[mi], bf[ni], acc[mi][ni], 0, 0, 0);
  }

  float* C = kvp + (size_t)ks * 256 * 2048;
  #pragma unroll
  for (int mi = 0; mi < 4; ++mi) {
    int r = m0 + wm * 64 + mi * 16 + lk * 4;
    #pragma unroll
    for (int ni = 0; ni < 4; ++ni) {
      int c = n0 + wn * 64 + ni * 16 + lr;
      #pragma unroll
      for (int jj = 0; jj < 4; ++jj)
        C[(size_t)(r + jj) * 2048 + c] = acc[mi][ni][jj];
    }
  }
}

// ---------------- attn (split-K sum + RoPE fused): grid (h=16, b=4), ao out bf16 ------------
__global__ __launch_bounds__(256)
void attn_kernel(const float* __restrict__ kvp, const float* __restrict__ lq,
                 __hip_bfloat16* __restrict__ aoB) {
  const int h = blockIdx.x, b = blockIdx.y;
  __shared__ float Ks[64][64];
  __shared__ float Vs[64][64];
  __shared__ float S[64][65];   // S[l][t]
  __shared__ float Pt[64][65];  // Pt[t][l]
  const int tid = threadIdx.x;

  {
    int r = tid >> 4;            // 0..15
    int c4 = (tid & 15) * 4;     // head-dim col (pairs i0=c4/2, i0+1)
    int i0 = c4 >> 1;
    float inv0 = exp2f(-13.287712379549449f * ((float)i0 * (1.0f / 32.0f)));
    float inv1 = exp2f(-13.287712379549449f * ((float)(i0 + 1) * (1.0f / 32.0f)));
    #pragma unroll
    for (int j = 0; j < 4; ++j) {
      int row = j * 16 + r;      // t
      float4 kf = make_float4(0.f, 0.f, 0.f, 0.f);
      float4 vf = make_float4(0.f, 0.f, 0.f, 0.f);
      #pragma unroll
      for (int ks = 0; ks < 8; ++ks) {
        const float* base = kvp + ((size_t)ks * 256 + b * 64 + row) * 2048 + h * 64;
        float4 kp = *(const float4*)(base + c4);
        float4 vp = *(const float4*)(base + 1024 + c4);
        kf.x += kp.x; kf.y += kp.y; kf.z += kp.z; kf.w += kp.w;
        vf.x += vp.x; vf.y += vp.y; vf.z += vp.z; vf.w += vp.w;
      }
      float a0 = (float)row * inv0, a1 = (float)row * inv1;
      float s0 = sinf(a0), c0 = cosf(a0), s1 = sinf(a1), c1 = cosf(a1);
      *(float4*)&Ks[row][c4] = make_float4(kf.x * c0 - kf.y * s0, kf.x * s0 + kf.y * c0,
                                           kf.z * c1 - kf.w * s1, kf.z * s1 + kf.w * c1);
      *(float4*)&Vs[row][c4] = vf;
    }
  }
  __syncthreads();

  // scores: thread = (l = lane, t-chunk = wave)
  {
    const int w = tid >> 6, l = tid & 63;
    float q[64];
    const float4* lq4 = (const float4*)(lq + ((size_t)l * 16 + h) * 64);
    #pragma unroll
    for (int i = 0; i < 16; ++i) {
      float4 f = lq4[i];
      q[4 * i] = f.x; q[4 * i + 1] = f.y; q[4 * i + 2] = f.z; q[4 * i + 3] = f.w;
    }
    #pragma unroll
    for (int tl = 0; tl < 16; ++tl) {
      int t = w * 16 + tl;
      float a = 0.f;
      #pragma unroll
      for (int d4 = 0; d4 < 16; ++d4) {
        float4 kf = *(const float4*)&Ks[t][d4 * 4];
        a += q[4 * d4] * kf.x + q[4 * d4 + 1] * kf.y + q[4 * d4 + 2] * kf.z + q[4 * d4 + 3] * kf.w;
      }
      S[l][t] = a * 0.125f;
    }
  }
  __syncthreads();

  // softmax: thread = (l = tid>>2, c = tid&3), causal t<=l
  {
    const int l = tid >> 2, c = tid & 3;
    float sv[16];
    float mx = -3.0e38f;
    #pragma unroll
    for (int i = 0; i < 16; ++i) {
      int t = c * 16 + i;
      sv[i] = S[l][t];
      if (t <= l) mx = fmaxf(mx, sv[i]);
    }
    mx = fmaxf(mx, __shfl_xor(mx, 1));
    mx = fmaxf(mx, __shfl_xor(mx, 2));
    float sum = 0.f;
    float e[16];
    #pragma unroll
    for (int i = 0; i < 16; ++i) {
      int t = c * 16 + i;
      e[i] = (t <= l) ? __expf(sv[i] - mx) : 0.f;
      sum += e[i];
    }
    sum += __shfl_xor(sum, 1);
    sum += __shfl_xor(sum, 2);
    float inv = 1.0f / sum;
    #pragma unroll
    for (int i = 0; i < 16; ++i) Pt[c * 16 + i][l] = e[i] * inv;
  }
  __syncthreads();

  // PV: thread = (l = lane, d-chunk = wave); write ao bf16 [l][d]
  {
    const int w = tid >> 6, l = tid & 63;
    float o[16];
    #pragma unroll
    for (int i = 0; i < 16; ++i) o[i] = 0.f;
    for (int t = 0; t < 64; ++t) {
      float p = Pt[t][l];
      #pragma unroll
      for (int d4 = 0; d4 < 4; ++d4) {
        float4 vf = *(const float4*)&Vs[t][w * 16 + d4 * 4];
        o[4 * d4]     += p * vf.x;
        o[4 * d4 + 1] += p * vf.y;
        o[4 * d4 + 2] += p * vf.z;
        o[4 * d4 + 3] += p * vf.w;
      }
    }
    union { __hip_bfloat16 h[16]; us8 v[2]; } u;
    #pragma unroll
    for (int i = 0; i < 16; ++i) u.h[i] = __float2bfloat16(o[i]);
    us8* dst = (us8*)(aoB + (((size_t)b * 16 + h) * 64 + l) * 64 + w * 16);
    dst[0] = u.v[0];
    dst[1] = u.v[1];
  }
}

// ---------------- Mt build via MFMA: Mt_slice[256c][64l] = WpT_slice[256c][64d] @ ao[64l][64d]^T
// Grid (4 ct, 16 h, 4 b), 256 thr, 4 waves along c. Proven gll16+swizzle staging geometry.
__global__ __launch_bounds__(256)
void build_mt_mfma(const __hip_bfloat16* __restrict__ aoB, const __hip_bfloat16* __restrict__ WpT,
                   __hip_bfloat16* __restrict__ Mt) {
  __shared__ __align__(16) unsigned short SW[256 * 64];
  __shared__ __align__(16) unsigned short SAo[64 * 64];
  const int ct = blockIdx.x, h = blockIdx.y, b = blockIdx.z;
  const int tid = threadIdx.x;
  const int lane = tid & 63;
  const int w = tid >> 6;            // wave 0..3, c-range w*64..w*64+63
  const int lr = lane & 15, lk = lane >> 4;

  // stage WpT slice [256c][64d]: 2048 chunks
  #pragma unroll
  for (int j = 0; j < 8; ++j) {
    int c2 = j * 256 + tid;
    int row = c2 >> 3, slot = c2 & 7;
    int gch = slot ^ (row & 7);
    gll16(WpT + (size_t)(ct * 256 + row) * 1024 + h * 64 + gch * 8, (char*)SW + c2 * 16);
  }
  // stage ao [64l][64d]: 512 chunks
  const __hip_bfloat16* aob = aoB + (((size_t)b * 16 + h) * 64) * 64;
  #pragma unroll
  for (int j = 0; j < 2; ++j) {
    int c2 = j * 256 + tid;
    int row = c2 >> 3, slot = c2 & 7;
    int gch = slot ^ (row & 7);
    gll16(aob + (size_t)row * 64 + gch * 8, (char*)SAo + c2 * 16);
  }
  __syncthreads();

  f32x4 acc[4][4] = {};
  bf16x8 bfr[2][4];
  #pragma unroll
  for (int kk = 0; kk < 2; ++kk)
    #pragma unroll
    for (int ni = 0; ni < 4; ++ni) {
      int row = ni * 16 + lr;
      int ch = (kk * 4 + lk) ^ (row & 7);
      bfr[kk][ni] = *(const bf16x8*)&SAo[row * 64 + ch * 8];
    }
  #pragma unroll
  for (int mi = 0; mi < 4; ++mi) {
    int row = w * 64 + mi * 16 + lr;
    int ch0 = lk ^ (row & 7);
    int ch1 = (4 + lk) ^ (row & 7);
    bf16x8 a0 = *(const bf16x8*)&SW[row * 64 + ch0 * 8];
    bf16x8 a1 = *(const bf16x8*)&SW[row * 64 + ch1 * 8];
    #pragma unroll
    for (int ni = 0; ni < 4; ++ni)
      acc[mi][ni] = __builtin_amdgcn_mfma_f32_16x16x32_bf16(a0, bfr[0][ni], acc[mi][ni], 0, 0, 0);
    #pragma unroll
    for (int ni = 0; ni < 4; ++ni)
      acc[mi][ni] = __builtin_amdgcn_mfma_f32_16x16x32_bf16(a1, bfr[1][ni], acc[mi][ni], 0, 0, 0);
  }

  // C-layout: row(c) = ct*256 + w*64 + mi*16 + lk*4 + jj, col(l) = ni*16 + lr
  #pragma unroll
  for (int mi = 0; mi < 4; ++mi) {
    int c = ct * 256 + w * 64 + mi * 16 + lk * 4;
    #pragma unroll
    for (int ni = 0; ni < 4; ++ni) {
      int l = ni * 16 + lr;
      #pragma unroll
      for (int jj = 0; jj < 4; ++jj)
        Mt[((size_t)b * 1024 + c + jj) * 1024 + h * 64 + l] = __float2bfloat16(acc[mi][ni][jj]);
    }
  }
}

extern "C" void kernel_launch(void* const* d_in, const int* in_sizes, int n_in,
                              void* d_out, int out_size, void* d_ws, size_t ws_size,
                              hipStream_t stream) {
  const float* x  = (const float*)d_in[0];
  const float* lq = (const float*)d_in[1];
  const float* Wk = (const float*)d_in[2];
  const float* Wv = (const float*)d_in[3];
  const float* Wg = (const float*)d_in[4];
  const float* Wp = (const float*)d_in[5];
  float* out = (float*)d_out;

  // workspace layout (bytes)
  char* w = (char*)d_ws;
  __hip_bfloat16* xb   = (__hip_bfloat16*)(w);              // 33,554,432
  __hip_bfloat16* G    = (__hip_bfloat16*)(w + 33554432);   // 33,554,432
  __hip_bfloat16* WgT  = (__hip_bfloat16*)(w + 67108864);   // 2,097,152
  __hip_bfloat16* WkvT = (__hip_bfloat16*)(w + 69206016);   // 4,194,304
  __hip_bfloat16* WpT  = (__hip_bfloat16*)(w + 73400320);   // 2,097,152
  __hip_bfloat16* Mt   = (__hip_bfloat16*)(w + 75497472);   // 8,388,608
  __hip_bfloat16* aoB  = (__hip_bfloat16*)(w + 83886080);   // 524,288
  // total 84,410,368 B
  // kv partials live in d_out (16MB of its 64MB), consumed by attn before the
  // final GEMM overwrites all of d_out. Deterministic.
  float* kvp = out;

  // x->bf16 + 4 weight transposes, one launch
  prep_kernel<<<6144, 256, 0, stream>>>(x, xb, Wg, Wk, Wv, Wp,
                                        WgT, WkvT, WkvT + 1024 * 1024, WpT);

  // gates: G = softmax_groups(x @ Wg), bf16 [16384,1024] (proven 2-phase, ~49us)
  gemm256<1><<<dim3(64, 4, 1), 512, 0, stream>>>(xb, WgT, G, 1024, 1024, 0LL, 0LL, 0LL);

  // k,v split-K partials: kvp[8][256][2048] fp32 (stacked rows b*64+t)
  gemm_kv<<<dim3(2, 16, 8), 256, 0, stream>>>(xb, WkvT, kvp);

  // attention (+partial sum +RoPE) -> ao bf16
  attn_kernel<<<dim3(16, 4), 256, 0, stream>>>(kvp, lq, aoB);

  // Mt via MFMA
  build_mt_mfma<<<dim3(4, 16, 4), 256, 0, stream>>>(aoB, WpT, Mt);

  // out[b] = G[b] @ Mt[b]^T (fp32 out, overwrites kvp scratch)
  gemm256<0><<<dim3(16, 4, 4), 512, 0, stream>>>(G, Mt, out, 1024, 1024,
                                                 4096LL * 1024, 1024LL * 1024, 4096LL * 1024);
}